// Round 3
// baseline (86.730 us; speedup 1.0000x reference)
//
#include <hip/hip_runtime.h>
#include <hip/hip_bf16.h>

#define IN_CAPS 32
#define OUT_CAPS 10
#define OUT_DIM 16
#define NOUT 160      // OUT_CAPS*OUT_DIM
#define KDIM 288
#define BATCH 4096
#define KSTEPS 9      // 288/32
#define CTILES 10     // 160/16
#define USTR 169      // LDS row stride for u (169 mod 32 = 9, coprime w/ 32 -> conflict-free)

typedef __bf16 bf16x8 __attribute__((ext_vector_type(8)));
typedef float  f32x4  __attribute__((ext_vector_type(4)));

// ---------------------------------------------------------------------------
// prep_w: W f32 [32][288][160] -> bf16 in per-lane MFMA B-fragment order:
//   Wf[((n*9+ks)*10+ct)*512 + lane*8 + j] = W[n][ks*32+(lane>>4)*8+j][ct*16+(lane&15)]
// ---------------------------------------------------------------------------
__global__ __launch_bounds__(256) void prep_w(const float* __restrict__ W,
                                              __bf16* __restrict__ Wf) {
    int f = blockIdx.x * 256 + threadIdx.x;   // grid covers exactly 32*9*10*512
    int j    = f & 7;
    int l    = (f >> 3) & 63;
    int rest = f >> 9;
    int c    = rest % CTILES;
    int tnk  = rest / CTILES;
    int ks   = tnk % KSTEPS;
    int n    = tnk / KSTEPS;
    int k    = ks * 32 + (l >> 4) * 8 + j;
    int col  = c * 16 + (l & 15);
    Wf[f] = (__bf16)W[(n * KDIM + k) * NOUT + col];
}

// ---------------------------------------------------------------------------
// gemm_u v2: 32 rows per wave (acc = 80 VGPR), launch_bounds(256,4) -> 4
// waves/SIMD for 2x memory-level parallelism vs R2. Grid (32 rowblocks, 32 n).
// ---------------------------------------------------------------------------
__global__ __launch_bounds__(256, 4) void gemm_u(const float* __restrict__ caps,
                                                 const __bf16* __restrict__ Wf,
                                                 __bf16* __restrict__ u) {
    const int n       = blockIdx.y;            // capsule 0..31
    const int wave    = threadIdx.x >> 6;      // 0..3
    const int lane    = threadIdx.x & 63;
    const int rowbase = blockIdx.x * 128 + wave * 32;   // 32 blocks * 4 waves * 32 = 4096
    const int lm      = lane & 15;
    const int lk      = lane >> 4;             // 0..3

    f32x4 acc[2][CTILES];
#pragma unroll
    for (int mt = 0; mt < 2; ++mt)
#pragma unroll
        for (int ct = 0; ct < CTILES; ++ct)
            acc[mt][ct] = (f32x4){0.f, 0.f, 0.f, 0.f};

    const __bf16* wfn = Wf + (size_t)n * (KSTEPS * CTILES * 512);

    for (int ks = 0; ks < KSTEPS; ++ks) {
        bf16x8 afr[2];
#pragma unroll
        for (int mt = 0; mt < 2; ++mt) {
            const float* src = caps + (size_t)(rowbase + mt * 16 + lm) * (IN_CAPS * KDIM)
                                    + n * KDIM + ks * 32 + lk * 8;
            f32x4 x0 = *(const f32x4*)(src);
            f32x4 x1 = *(const f32x4*)(src + 4);
            bf16x8 a;
            a[0] = (__bf16)x0[0]; a[1] = (__bf16)x0[1];
            a[2] = (__bf16)x0[2]; a[3] = (__bf16)x0[3];
            a[4] = (__bf16)x1[0]; a[5] = (__bf16)x1[1];
            a[6] = (__bf16)x1[2]; a[7] = (__bf16)x1[3];
            afr[mt] = a;
        }
        const __bf16* wks = wfn + (size_t)ks * (CTILES * 512) + lane * 8;
#pragma unroll
        for (int ct = 0; ct < CTILES; ++ct) {
            bf16x8 bfr = *(const bf16x8*)(wks + ct * 512);
#pragma unroll
            for (int mt = 0; mt < 2; ++mt)
                acc[mt][ct] = __builtin_amdgcn_mfma_f32_16x16x32_bf16(afr[mt], bfr, acc[mt][ct], 0, 0, 0);
        }
    }

    // C/D mapping: col = lane&15, row = (lane>>4)*4 + reg
#pragma unroll
    for (int mt = 0; mt < 2; ++mt)
#pragma unroll
        for (int ct = 0; ct < CTILES; ++ct)
#pragma unroll
            for (int r = 0; r < 4; ++r) {
                int row = rowbase + mt * 16 + lk * 4 + r;
                int col = ct * 16 + lm;
                u[((size_t)row * IN_CAPS + n) * NOUT + col] = (__bf16)acc[mt][ct][r];
            }
}

// ---------------------------------------------------------------------------
// routing v2: 2 batch elements per block (two 128-thread groups).
// u[b] (32x160) -> LDS f32 (stride 169), then 4 routing iterations in LDS.
// ---------------------------------------------------------------------------
__global__ __launch_bounds__(256) void routing(const __bf16* __restrict__ u,
                                               const float* __restrict__ bbias,
                                               float* __restrict__ out) {
    __shared__ float ul[2][IN_CAPS * USTR];       // 43264 B
    __shared__ float bl[2][IN_CAPS * OUT_CAPS];
    __shared__ float cs[2][IN_CAPS * OUT_CAPS];
    __shared__ float ss[2][NOUT];
    __shared__ float vs[2][NOUT];
    __shared__ float scale_s[2][OUT_CAPS];

    const int t  = threadIdx.x;
    const int gb = t >> 7;                        // group 0/1
    const int g  = t & 127;                       // index within group
    const size_t b = (size_t)blockIdx.x * 2 + gb;
    const __bf16* ub = u + b * (IN_CAPS * NOUT);

    // load u[b] -> LDS f32, 8 bf16 per 16B chunk, 640 chunks over 128 threads
    for (int cc = g; cc < 640; cc += 128) {
        int n = cc / 20;
        int rem = cc - n * 20;
        uint4 raw = *(const uint4*)(ub + cc * 8);
        bf16x8 bv = __builtin_bit_cast(bf16x8, raw);
#pragma unroll
        for (int j = 0; j < 8; ++j) ul[gb][n * USTR + rem * 8 + j] = (float)bv[j];
    }
    for (int p = g; p < IN_CAPS * OUT_CAPS; p += 128) bl[gb][p] = bbias[p];
    __syncthreads();

    for (int it = 0; it < 4; ++it) {
        if (it > 0) {
            // agreement: bl[n][o] += sum_d u[n][o*16+d] * v[o*16+d]
            for (int p = g; p < IN_CAPS * OUT_CAPS; p += 128) {
                int n = p & 31;
                int o = p >> 5;
                float a = 0.f;
#pragma unroll
                for (int d = 0; d < 16; ++d)
                    a += ul[gb][n * USTR + o * 16 + d] * vs[gb][o * 16 + d];
                bl[gb][n * 10 + o] += a;
            }
            __syncthreads();
        }
        // softmax over o per n
        if (g < IN_CAPS) {
            float m = bl[gb][g * 10];
#pragma unroll
            for (int o = 1; o < 10; ++o) m = fmaxf(m, bl[gb][g * 10 + o]);
            float e[10];
            float sum = 0.f;
#pragma unroll
            for (int o = 0; o < 10; ++o) { e[o] = __expf(bl[gb][g * 10 + o] - m); sum += e[o]; }
            float inv = 1.0f / sum;
#pragma unroll
            for (int o = 0; o < 10; ++o) cs[gb][g * 10 + o] = e[o] * inv;
        }
        __syncthreads();
        // s[o][d] = sum_n c[n][o] * u[n][o*16+d]
        for (int p = g; p < NOUT; p += 128) {
            int o = p >> 4;
            float acc = 0.f;
#pragma unroll
            for (int n = 0; n < IN_CAPS; ++n)
                acc += cs[gb][n * 10 + o] * ul[gb][n * USTR + p];
            ss[gb][p] = acc;
        }
        __syncthreads();
        // squash scale per o
        if (g < OUT_CAPS) {
            float sq = 0.f;
#pragma unroll
            for (int d = 0; d < 16; ++d) { float x = ss[gb][g * 16 + d]; sq += x * x; }
            scale_s[gb][g] = sq / ((1.0f + sq) * sqrtf(sq));
        }
        __syncthreads();
        for (int p = g; p < NOUT; p += 128) vs[gb][p] = scale_s[gb][p >> 4] * ss[gb][p];
        __syncthreads();
    }

    for (int p = g; p < NOUT; p += 128) out[b * NOUT + p] = vs[gb][p];
}

// ---------------------------------------------------------------------------
extern "C" void kernel_launch(void* const* d_in, const int* in_sizes, int n_in,
                              void* d_out, int out_size, void* d_ws, size_t ws_size,
                              hipStream_t stream) {
    const float* caps  = (const float*)d_in[0];   // [4096][32][288]
    const float* W     = (const float*)d_in[1];   // [32][288][160]
    const float* bbias = (const float*)d_in[2];   // [32][10]
    float* out = (float*)d_out;                   // [4096][10][16]

    __bf16* Wf = (__bf16*)d_ws;                               // 2,949,120 B
    __bf16* u  = (__bf16*)((char*)d_ws + 2949120);            // 41,943,040 B

    prep_w<<<dim3(5760), dim3(256), 0, stream>>>(W, Wf);
    gemm_u<<<dim3(32, 32), dim3(256), 0, stream>>>(caps, Wf, u);
    routing<<<dim3(BATCH / 2), dim3(256), 0, stream>>>(u, bbias, out);
}

// Round 4
// 82.215 us; speedup vs baseline: 1.0549x; 1.0549x over previous
//
#include <hip/hip_runtime.h>
#include <hip/hip_bf16.h>

#define IN_CAPS 32
#define OUT_CAPS 10
#define NOUT 160      // OUT_CAPS*OUT_DIM
#define KDIM 288
#define BATCH 4096
#define KSTEPS 9      // 288/32
#define CTILES 10     // 160/16
#define STR2 162      // LDS ushort stride for u rows in routing

typedef __bf16 bf16x8 __attribute__((ext_vector_type(8)));
typedef float  f32x4  __attribute__((ext_vector_type(4)));

// ---------------------------------------------------------------------------
// prep_w: W f32 [32][288][160] -> bf16 in per-lane MFMA B-fragment order:
//   Wf[((n*9+ks)*10+ct)*512 + lane*8 + j] = W[n][ks*32+(lane>>4)*8+j][ct*16+(lane&15)]
// ---------------------------------------------------------------------------
__global__ __launch_bounds__(256) void prep_w(const float* __restrict__ W,
                                              __bf16* __restrict__ Wf) {
    int f = blockIdx.x * 256 + threadIdx.x;   // grid covers exactly 32*9*10*512
    int j    = f & 7;
    int l    = (f >> 3) & 63;
    int rest = f >> 9;
    int c    = rest % CTILES;
    int tnk  = rest / CTILES;
    int ks   = tnk % KSTEPS;
    int n    = tnk / KSTEPS;
    int k    = ks * 32 + (l >> 4) * 8 + j;
    int col  = c * 16 + (l & 15);
    Wf[f] = (__bf16)W[(n * KDIM + k) * NOUT + col];
}

// ---------------------------------------------------------------------------
// gemm_u v3: 32 rows/wave, NO min-waves force (R3 lesson: launch_bounds(256,4)
// forced acc spill -> 88us). Explicit A-prefetch double buffer. Epilogue:
// permuted fully-coalesced 16B stores; chunk layout (16B units):
//   idx = (((n*128 + rw)*2 + mt)*5 + p)*64 + lane
//   chunk[j] = acc[mt][2p + (j>>2)][j&3]  => row = rw*32+mt*16+lk*4+(j&3),
//                                            col = (2p+(j>>2))*16 + lm
// ---------------------------------------------------------------------------
__global__ __launch_bounds__(256) void gemm_u(const float* __restrict__ caps,
                                              const __bf16* __restrict__ Wf,
                                              uint4* __restrict__ up) {
    const int n    = blockIdx.y;               // capsule 0..31
    const int wave = threadIdx.x >> 6;
    const int lane = threadIdx.x & 63;
    const int rw   = blockIdx.x * 4 + wave;    // 32-row block id, 0..127
    const int lm   = lane & 15;
    const int lk   = lane >> 4;

    f32x4 acc[2][CTILES];
#pragma unroll
    for (int mt = 0; mt < 2; ++mt)
#pragma unroll
        for (int ct = 0; ct < CTILES; ++ct)
            acc[mt][ct] = (f32x4){0.f, 0.f, 0.f, 0.f};

    const float* a0 = caps + (size_t)(rw * 32 + lm) * (IN_CAPS * KDIM) + n * KDIM + lk * 8;
    const float* a1 = a0 + (size_t)16 * (IN_CAPS * KDIM);
    const __bf16* wfn = Wf + (size_t)n * (KSTEPS * CTILES * 512) + lane * 8;

    // prefetch ks=0 A raws
    f32x4 pre[4];
    pre[0] = *(const f32x4*)(a0);
    pre[1] = *(const f32x4*)(a0 + 4);
    pre[2] = *(const f32x4*)(a1);
    pre[3] = *(const f32x4*)(a1 + 4);

    for (int ks = 0; ks < KSTEPS; ++ks) {
        // convert current A raws to bf16 fragments
        bf16x8 afr[2];
#pragma unroll
        for (int mt = 0; mt < 2; ++mt) {
            bf16x8 a;
            a[0] = (__bf16)pre[2*mt][0]; a[1] = (__bf16)pre[2*mt][1];
            a[2] = (__bf16)pre[2*mt][2]; a[3] = (__bf16)pre[2*mt][3];
            a[4] = (__bf16)pre[2*mt+1][0]; a[5] = (__bf16)pre[2*mt+1][1];
            a[6] = (__bf16)pre[2*mt+1][2]; a[7] = (__bf16)pre[2*mt+1][3];
            afr[mt] = a;
        }
        // issue next-ks A loads (latency hides under the 20 MFMAs below)
        if (ks + 1 < KSTEPS) {
            const float* n0 = a0 + (ks + 1) * 32;
            const float* n1 = a1 + (ks + 1) * 32;
            pre[0] = *(const f32x4*)(n0);
            pre[1] = *(const f32x4*)(n0 + 4);
            pre[2] = *(const f32x4*)(n1);
            pre[3] = *(const f32x4*)(n1 + 4);
        }
        const __bf16* wks = wfn + (size_t)ks * (CTILES * 512);
#pragma unroll
        for (int ct = 0; ct < CTILES; ++ct) {
            bf16x8 bfr = *(const bf16x8*)(wks + ct * 512);
            acc[0][ct] = __builtin_amdgcn_mfma_f32_16x16x32_bf16(afr[0], bfr, acc[0][ct], 0, 0, 0);
            acc[1][ct] = __builtin_amdgcn_mfma_f32_16x16x32_bf16(afr[1], bfr, acc[1][ct], 0, 0, 0);
        }
    }

    // permuted coalesced store: 10 x 16B per lane, 1KB contiguous per instr
    const size_t cbase = (((size_t)n * 128 + rw) * 2) * 5 * 64 + lane;
#pragma unroll
    for (int mt = 0; mt < 2; ++mt)
#pragma unroll
        for (int p = 0; p < 5; ++p) {
            bf16x8 pk;
#pragma unroll
            for (int j = 0; j < 8; ++j)
                pk[j] = (__bf16)acc[mt][2 * p + (j >> 2)][j & 3];
            up[cbase + ((size_t)mt * 5 + p) * 64] = __builtin_bit_cast(uint4, pk);
        }
}

// ---------------------------------------------------------------------------
// routing v3: 4 consecutive batch rows per block (one 64-thread group each).
// Coalesced uint4 loads of u_perm, decode-scatter to bf16 LDS.
// ---------------------------------------------------------------------------
__global__ __launch_bounds__(256) void routing(const uint4* __restrict__ up,
                                               const float* __restrict__ bbias,
                                               float* __restrict__ out) {
    __shared__ __bf16 ul[4][IN_CAPS * STR2];      // 41472 B
    __shared__ float  bl[4][IN_CAPS * OUT_CAPS];  // 5120 B
    __shared__ float  cs[4][IN_CAPS * OUT_CAPS];  // 5120 B
    __shared__ float  ss[4][NOUT];                // 2560 B
    __shared__ float  vs[4][NOUT];                // 2560 B
    __shared__ float  scale_s[4][16];             // 256 B   => ~57 KB total

    const int t  = threadIdx.x;
    const int b0 = blockIdx.x * 4;
    const int rw = b0 >> 5;
    const int mt = (b0 >> 4) & 1;
    const int lk = (b0 >> 2) & 3;

    // load u_perm for rows b0..b0+3: 32n * 5p * 16lm = 2560 chunks of 16B
    for (int c = t; c < 2560; c += 256) {
        int n   = c / 80;
        int rem = c - n * 80;
        int p   = rem >> 4;
        int lm  = rem & 15;
        size_t idx = ((((size_t)n * 128 + rw) * 2 + mt) * 5 + p) * 64 + lk * 16 + lm;
        bf16x8 v = __builtin_bit_cast(bf16x8, up[idx]);
#pragma unroll
        for (int j = 0; j < 8; ++j) {
            int ct = 2 * p + (j >> 2);
            int rr = j & 3;
            ul[rr][n * STR2 + ct * 16 + lm] = v[j];
        }
    }
    const int grp = t >> 6;     // local row 0..3 -> batch element b0+grp
    const int g   = t & 63;
    for (int pp = g; pp < IN_CAPS * OUT_CAPS; pp += 64) bl[grp][pp] = bbias[pp];
    __syncthreads();

    for (int it = 0; it < 4; ++it) {
        if (it > 0) {
            // agreement: bl[n][o] += sum_d u[n][o*16+d] * v[o*16+d]
            for (int pp = g; pp < IN_CAPS * OUT_CAPS; pp += 64) {
                int n = pp & 31;
                int o = pp >> 5;
                float a = 0.f;
#pragma unroll
                for (int d = 0; d < 16; ++d)
                    a += (float)ul[grp][n * STR2 + o * 16 + d] * vs[grp][o * 16 + d];
                bl[grp][n * 10 + o] += a;
            }
            __syncthreads();
        }
        // softmax over o per n
        if (g < IN_CAPS) {
            float m = bl[grp][g * 10];
#pragma unroll
            for (int o = 1; o < 10; ++o) m = fmaxf(m, bl[grp][g * 10 + o]);
            float e[10];
            float sum = 0.f;
#pragma unroll
            for (int o = 0; o < 10; ++o) { e[o] = __expf(bl[grp][g * 10 + o] - m); sum += e[o]; }
            float inv = 1.0f / sum;
#pragma unroll
            for (int o = 0; o < 10; ++o) cs[grp][g * 10 + o] = e[o] * inv;
        }
        __syncthreads();
        // s[o][d] = sum_n c[n][o] * u[n][o*16+d]
        for (int p = g; p < NOUT; p += 64) {
            int o = p >> 4;
            float a = 0.f;
#pragma unroll
            for (int n = 0; n < IN_CAPS; ++n)
                a += cs[grp][n * 10 + o] * (float)ul[grp][n * STR2 + p];
            ss[grp][p] = a;
        }
        __syncthreads();
        // squash scale per o
        if (g < OUT_CAPS) {
            float sq = 0.f;
#pragma unroll
            for (int d = 0; d < 16; ++d) { float x = ss[grp][g * 16 + d]; sq += x * x; }
            scale_s[grp][g] = sq / ((1.0f + sq) * sqrtf(sq));
        }
        __syncthreads();
        for (int p = g; p < NOUT; p += 64) vs[grp][p] = scale_s[grp][p >> 4] * ss[grp][p];
        __syncthreads();
    }

    for (int p = g; p < NOUT; p += 64)
        out[(size_t)(b0 + grp) * NOUT + p] = vs[grp][p];
}

// ---------------------------------------------------------------------------
extern "C" void kernel_launch(void* const* d_in, const int* in_sizes, int n_in,
                              void* d_out, int out_size, void* d_ws, size_t ws_size,
                              hipStream_t stream) {
    const float* caps  = (const float*)d_in[0];   // [4096][32][288]
    const float* W     = (const float*)d_in[1];   // [32][288][160]
    const float* bbias = (const float*)d_in[2];   // [32][10]
    float* out = (float*)d_out;                   // [4096][10][16]

    __bf16* Wf = (__bf16*)d_ws;                               // 2,949,120 B
    uint4*  up = (uint4*)((char*)d_ws + 2949120);             // 41,943,040 B

    prep_w<<<dim3(5760), dim3(256), 0, stream>>>(W, Wf);
    gemm_u<<<dim3(32, 32), dim3(256), 0, stream>>>(caps, Wf, up);
    routing<<<dim3(BATCH / 4), dim3(256), 0, stream>>>(up, bbias, out);
}